// Round 3
// baseline (1689.785 us; speedup 1.0000x reference)
//
#include <hip/hip_runtime.h>

// Instant-NGP style multires hash encoding.
// N=2^20 points, 16 levels, table 2^19 entries x 2 features (float32).
//
// SEMANTICS LEDGER (established R2-R5 of previous session):
//  - R3 == R4 bit-identical => device IEEE f32 div == faithful f32 emulation.
//    That FAILED => ground truth q-path is NOT plain f32 op-by-op.
//  - R5 exact-rational (== float64 semantics) FAILED => not f64 either.
//  - Everything else (corners, wrap, uint32 hash mod 2^19, weights, layout)
//    is precision-robust; floor/lc f32-vs-f64 flips are continuity-protected
//    (error ~3e-9 << 2e-6 threshold).
//  => Remaining candidate: XLA algebraic-simplifier rewrite of the eager jnp
//     reference: divide-by-constant -> multiply by constant-folded reciprocal:
//       v = RN32( c * RN32(1/res) )   (exact for pow2 res, differs for the
//     11 non-pow2 resolutions at a few % of coords -> sparse hash flips ->
//     the persistent ~1.7-1.8e-4 absmax signature).
//
// q is built as a COMPILE-TIME constexpr table: clang constexpr float math is
// strict IEEE op-by-op (no -ffp-contract=fast FMA fusion, which would corrupt
// c*r+1 on device). Staged to LDS at block start (machinery validated in R4:
// table path was bit-identical to device computation).
//
// RESOLUTIONS trap: int(16 * 32**(9/15)) == 127, NOT 128 (9/15 rounds below
// 0.6 in double; pow -> 7.9999999999999991). Verified analytically with
// <=0.52-ulp pow error margins; levels 32/64/256 robustly safe.
//
// R0-R2 (this session): cache-policy partitioning by reuse class.
//  - Gather footprints per level (distinct 64B lines): L0~0.25MB L1~0.5MB
//    L2~1MB L3~2MB, L4+ = 2.6..4MB. Only L0-L3 (~3.75MB) can be L2-resident
//    per XCD (4MB). NT-load levels >=4, NT-store output, NT-load x so the
//    streams stop evicting the small resident tables. Values bit-identical.
//  - R2 fix: __builtin_nontemporal_load rejects HIP_vector_type float2
//    (class, not clang vector) -> gather through ext_vector_type(2) float.

static constexpr int      kNLevels   = 16;
static constexpr unsigned kTableSize = 1u << 19;
static constexpr unsigned kMask      = kTableSize - 1u;
static constexpr unsigned kP1        = 2654435761u;
static constexpr unsigned kP2        = 805459861u;

typedef float v4f __attribute__((ext_vector_type(4)));
typedef float v2f __attribute__((ext_vector_type(2)));

// int(16 * 32**(i/15)) with exact Python-double semantics (note 127!)
constexpr int RES_[kNLevels]  = {16, 20, 25, 32, 40, 50, 64, 80,
                                 101, 127, 161, 203, 256, 322, 406, 512};
constexpr int QOFF_[kNLevels] = {0, 16, 36, 61, 93, 133, 183, 247,
                                 327, 428, 555, 716, 919, 1175, 1497, 1903};
static constexpr int kQTot = 2415;  // sum of RES_

// q(c,res) under XLA reciprocal-multiply semantics:
//   r = RN32(1/res); v = RN32(c*r); q = trunc(((v+1)*0.5)*262144)
// constexpr evaluation = strict IEEE f32 per op, no contraction.
constexpr unsigned qval_rcp(int c, int res) {
    const float r = 1.0f / (float)res;          // correctly rounded f32
    const float v = (float)c * r;               // correctly rounded f32 mul
    const float s = ((v + 1.0f) * 0.5f) * 262144.0f;  // +1 rounds; pow2 muls exact
    return (unsigned)s;                          // trunc toward zero
}

struct QTab {
    unsigned v[kQTot];
    constexpr QTab() : v{} {
        int o = 0;
        for (int i = 0; i < kNLevels; ++i) {
            for (int c = 0; c < RES_[i]; ++c) v[o + c] = qval_rcp(c, RES_[i]);
            o += RES_[i];
        }
    }
};
__constant__ QTab QT = QTab();

__global__ __launch_bounds__(256) void hashenc_kernel(
    const float* __restrict__ x,
    const float* __restrict__ tables,
    float* __restrict__ out,
    int N)
{
    __shared__ unsigned sq[kQTot];
    for (int t = threadIdx.x; t < kQTot; t += 256) sq[t] = QT.v[t];
    __syncthreads();

    const int n = blockIdx.x * 256 + threadIdx.x;
    if (n >= N) return;

    // x is streamed exactly once -> non-temporal
    float px = __builtin_nontemporal_load(&x[3 * n + 0]);
    float py = __builtin_nontemporal_load(&x[3 * n + 1]);
    float pz = __builtin_nontemporal_load(&x[3 * n + 2]);
    px = fminf(fmaxf(px, -1.0f), 1.0f);
    py = fminf(fmaxf(py, -1.0f), 1.0f);
    pz = fminf(fmaxf(pz, -1.0f), 1.0f);

    float o[2 * kNLevels];

#pragma unroll
    for (int i = 0; i < kNLevels; ++i) {
        const int   res  = RES_[i];
        const float resf = (float)res;
        const unsigned* qt = sq + QOFF_[i];

        // coords, floor, frac (f32, matches reference op-for-op; boundary
        // flips vs higher precision are continuity-protected)
        const float cxf = px * resf, cyf = py * resf, czf = pz * resf;
        const float fx = floorf(cxf), fy = floorf(cyf), fz = floorf(czf);
        const float lx = cxf - fx, ly = cyf - fy, lz = czf - fz;

        // integer corner coords wrapped into [0, res). floor(x*res) in [-res, res].
        const int ix = (int)fx, iy = (int)fy, iz = (int)fz;
        const int cx0 = ix < 0 ? ix + res : (ix >= res ? ix - res : ix);
        const int cy0 = iy < 0 ? iy + res : (iy >= res ? iy - res : iy);
        const int cz0 = iz < 0 ? iz + res : (iz >= res ? iz - res : iz);
        const int cx1 = (cx0 + 1 == res) ? 0 : cx0 + 1;
        const int cy1 = (cy0 + 1 == res) ? 0 : cy0 + 1;
        const int cz1 = (cz0 + 1 == res) ? 0 : cz0 + 1;

        // quantized hash inputs: LDS lookup of the precomputed rcp-mul q
        const unsigned qx0 = qt[cx0], qx1 = qt[cx1];
        const unsigned qy0 = qt[cy0], qy1 = qt[cy1];
        const unsigned qz0 = qt[cz0], qz1 = qt[cz1];

        const unsigned hy0 = qy0 * kP1, hy1 = qy1 * kP1;
        const unsigned hz0 = qz0 * kP2, hz1 = qz1 * kP2;

        // trilinear weights; offset bit2->x(dim0), bit1->y(dim1), bit0->z(dim2)
        const float wx0 = 1.0f - lx, wx1 = lx;
        const float wy0 = 1.0f - ly, wy1 = ly;
        const float wz0 = 1.0f - lz, wz1 = lz;

        unsigned idx[8];
        float    w[8];
#pragma unroll
        for (int m = 0; m < 8; ++m) {
            const unsigned h = ((m & 4) ? qx1 : qx0) +
                               ((m & 2) ? hy1 : hy0) +
                               ((m & 1) ? hz1 : hz0);
            idx[m] = h & kMask;
            w[m] = (((m & 4) ? wx1 : wx0) * ((m & 2) ? wy1 : wy0)) *
                   ((m & 1) ? wz1 : wz0);
        }

        // gather through clang ext-vector float2 (NT builtin requires
        // scalar/pointer/ext-vector element type; HIP float2 is a class)
        const v2f* tb = (const v2f*)tables + (size_t)i * kTableSize;

        // Cache-policy partition: levels 0-3 (~3.75MB total line footprint)
        // stay default (L2-resident per XCD); levels >=4 can't fit -> NT so
        // they don't evict the resident set. i is compile-time constant
        // (full unroll), so the branch folds away.
        v2f f[8];
#pragma unroll
        for (int m = 0; m < 8; ++m) {
            if (i >= 4) f[m] = __builtin_nontemporal_load(&tb[idx[m]]);
            else        f[m] = tb[idx[m]];
        }

        float a0 = 0.0f, a1 = 0.0f;
#pragma unroll
        for (int m = 0; m < 8; ++m) {
            a0 += w[m] * f[m].x;
            a1 += w[m] * f[m].y;
        }
        o[2 * i + 0] = a0;
        o[2 * i + 1] = a1;
    }

    // 32 contiguous floats per point -> 8 x 16B stores; output is streamed
    // once with zero reuse -> non-temporal (don't churn L2 capacity)
    v4f* op = (v4f*)(out + (size_t)n * (2 * kNLevels));
#pragma unroll
    for (int k = 0; k < 8; ++k) {
        v4f v = {o[4 * k + 0], o[4 * k + 1], o[4 * k + 2], o[4 * k + 3]};
        __builtin_nontemporal_store(v, &op[k]);
    }
}

extern "C" void kernel_launch(void* const* d_in, const int* in_sizes, int n_in,
                              void* d_out, int out_size, void* d_ws, size_t ws_size,
                              hipStream_t stream) {
    const float* x      = (const float*)d_in[0];
    const float* tables = (const float*)d_in[1];
    float*       out    = (float*)d_out;
    const int N = in_sizes[0] / 3;
    const int blocks = (N + 255) / 256;
    hipLaunchKernelGGL(hashenc_kernel, dim3(blocks), dim3(256), 0, stream,
                       x, tables, out, N);
}

// Round 4
// 1022.252 us; speedup vs baseline: 1.6530x; 1.6530x over previous
//
#include <hip/hip_runtime.h>

// Instant-NGP style multires hash encoding.
// N=2^20 points, 16 levels, table 2^19 entries x 2 features (float32).
//
// SEMANTICS LEDGER (established R2-R5 of previous session):
//  - q-path semantics: XLA reciprocal-multiply rewrite, constexpr-precomputed
//    table (strict IEEE f32 per op, no FMA contraction). Verified: absmax
//    4.8e-07 (R3 this session) -- well inside threshold.
//  - corners/wrap/uint32 hash mod 2^19/weights/layout are precision-robust.
//
// RESOLUTIONS trap: int(16 * 32**(9/15)) == 127, NOT 128.
//
// R3 POST-MORTEM (this session):
//  - NT loads on level>=4 gathers: FETCH_SIZE 4.0GB/dispatch (vs ~76MB ideal),
//    dur 962 -> 1550us. NT = no-allocate in L2/LLC; but every table line has
//    ~128x reuse (8.4M gathers over 65K lines/level) that the 256MB L3 was
//    absorbing. NT killed L3 residency => REVERTED. Tables must stay cacheable.
//  - NT stores: WRITE_SIZE 347MB vs 134MB ideal (sub-line write amplification)
//    => REVERTED.
//  - Profile of gather path: VALUBusy 2.7%, HBM 35%, occupancy 74%, VGPR=32.
//    Not compute-, not HBM-BW-bound: bound on gather latency/transactions.
//    VGPR=32 => compiler serializes levels (only 8 loads in flight).
//
// R4: MLP restructure -- process levels in PAIRS: compute idx/w for two
// levels, issue all 16 global_load_dwordx2 back-to-back, then accumulate.
// __launch_bounds__(256,6): VGPR cap ~85 (512-reg pool/SIMD / 6 waves),
// keeps 6 waves/SIMD = 24/CU = the measured 74% occupancy, doubles
// loads-in-flight. Store each pair's v4f immediately (no o[32] buffer).

static constexpr int      kNLevels   = 16;
static constexpr unsigned kTableSize = 1u << 19;
static constexpr unsigned kMask      = kTableSize - 1u;
static constexpr unsigned kP1        = 2654435761u;
static constexpr unsigned kP2        = 805459861u;

typedef float v4f __attribute__((ext_vector_type(4)));
typedef float v2f __attribute__((ext_vector_type(2)));

// int(16 * 32**(i/15)) with exact Python-double semantics (note 127!)
constexpr int RES_[kNLevels]  = {16, 20, 25, 32, 40, 50, 64, 80,
                                 101, 127, 161, 203, 256, 322, 406, 512};
constexpr int QOFF_[kNLevels] = {0, 16, 36, 61, 93, 133, 183, 247,
                                 327, 428, 555, 716, 919, 1175, 1497, 1903};
static constexpr int kQTot = 2415;  // sum of RES_

// q(c,res) under XLA reciprocal-multiply semantics:
//   r = RN32(1/res); v = RN32(c*r); q = trunc(((v+1)*0.5)*262144)
// constexpr evaluation = strict IEEE f32 per op, no contraction.
constexpr unsigned qval_rcp(int c, int res) {
    const float r = 1.0f / (float)res;          // correctly rounded f32
    const float v = (float)c * r;               // correctly rounded f32 mul
    const float s = ((v + 1.0f) * 0.5f) * 262144.0f;  // +1 rounds; pow2 muls exact
    return (unsigned)s;                          // trunc toward zero
}

struct QTab {
    unsigned v[kQTot];
    constexpr QTab() : v{} {
        int o = 0;
        for (int i = 0; i < kNLevels; ++i) {
            for (int c = 0; c < RES_[i]; ++c) v[o + c] = qval_rcp(c, RES_[i]);
            o += RES_[i];
        }
    }
};
__constant__ QTab QT = QTab();

// Per-level index + weight computation. Called with compile-time-constant i
// (enclosing loop fully unrolled), so RES_/QOFF_ fold to immediates.
__device__ __forceinline__ void level_idx_w(
    const int i, const unsigned* __restrict__ sq,
    const float px, const float py, const float pz,
    unsigned* __restrict__ idx, float* __restrict__ w)
{
    const int   res  = RES_[i];
    const float resf = (float)res;
    const unsigned* qt = sq + QOFF_[i];

    // coords, floor, frac (f32; boundary flips continuity-protected)
    const float cxf = px * resf, cyf = py * resf, czf = pz * resf;
    const float fx = floorf(cxf), fy = floorf(cyf), fz = floorf(czf);
    const float lx = cxf - fx, ly = cyf - fy, lz = czf - fz;

    // integer corner coords wrapped into [0, res). floor(x*res) in [-res, res].
    const int ix = (int)fx, iy = (int)fy, iz = (int)fz;
    const int cx0 = ix < 0 ? ix + res : (ix >= res ? ix - res : ix);
    const int cy0 = iy < 0 ? iy + res : (iy >= res ? iy - res : iy);
    const int cz0 = iz < 0 ? iz + res : (iz >= res ? iz - res : iz);
    const int cx1 = (cx0 + 1 == res) ? 0 : cx0 + 1;
    const int cy1 = (cy0 + 1 == res) ? 0 : cy0 + 1;
    const int cz1 = (cz0 + 1 == res) ? 0 : cz0 + 1;

    // quantized hash inputs: LDS lookup of the precomputed rcp-mul q
    const unsigned qx0 = qt[cx0], qx1 = qt[cx1];
    const unsigned qy0 = qt[cy0], qy1 = qt[cy1];
    const unsigned qz0 = qt[cz0], qz1 = qt[cz1];

    const unsigned hy0 = qy0 * kP1, hy1 = qy1 * kP1;
    const unsigned hz0 = qz0 * kP2, hz1 = qz1 * kP2;

    // trilinear weights; offset bit2->x(dim0), bit1->y(dim1), bit0->z(dim2)
    const float wx0 = 1.0f - lx, wx1 = lx;
    const float wy0 = 1.0f - ly, wy1 = ly;
    const float wz0 = 1.0f - lz, wz1 = lz;

#pragma unroll
    for (int m = 0; m < 8; ++m) {
        const unsigned h = ((m & 4) ? qx1 : qx0) +
                           ((m & 2) ? hy1 : hy0) +
                           ((m & 1) ? hz1 : hz0);
        idx[m] = h & kMask;
        w[m] = (((m & 4) ? wx1 : wx0) * ((m & 2) ? wy1 : wy0)) *
               ((m & 1) ? wz1 : wz0);
    }
}

__global__ __launch_bounds__(256, 6) void hashenc_kernel(
    const float* __restrict__ x,
    const float* __restrict__ tables,
    float* __restrict__ out,
    int N)
{
    __shared__ unsigned sq[kQTot];
    for (int t = threadIdx.x; t < kQTot; t += 256) sq[t] = QT.v[t];
    __syncthreads();

    const int n = blockIdx.x * 256 + threadIdx.x;
    if (n >= N) return;

    float px = x[3 * n + 0];
    float py = x[3 * n + 1];
    float pz = x[3 * n + 2];
    px = fminf(fmaxf(px, -1.0f), 1.0f);
    py = fminf(fmaxf(py, -1.0f), 1.0f);
    pz = fminf(fmaxf(pz, -1.0f), 1.0f);

    v4f* op = (v4f*)(out + (size_t)n * (2 * kNLevels));

    // Levels in pairs: 16 independent gathers in flight per iteration
    // (vs 8 before). Each pair's two float2 outputs = one 16B store.
#pragma unroll
    for (int ip = 0; ip < kNLevels / 2; ++ip) {
        const int iA = 2 * ip, iB = 2 * ip + 1;

        unsigned ia[8], ib[8];
        float    wa[8], wb[8];
        level_idx_w(iA, sq, px, py, pz, ia, wa);
        level_idx_w(iB, sq, px, py, pz, ib, wb);

        const v2f* tA = (const v2f*)tables + (size_t)iA * kTableSize;
        const v2f* tB = (const v2f*)tables + (size_t)iB * kTableSize;

        v2f fa[8], fb[8];
#pragma unroll
        for (int m = 0; m < 8; ++m) fa[m] = tA[ia[m]];
#pragma unroll
        for (int m = 0; m < 8; ++m) fb[m] = tB[ib[m]];

        // per-level accumulation order identical to reference-verified path
        float a0 = 0.0f, a1 = 0.0f, b0 = 0.0f, b1 = 0.0f;
#pragma unroll
        for (int m = 0; m < 8; ++m) {
            a0 += wa[m] * fa[m].x;
            a1 += wa[m] * fa[m].y;
        }
#pragma unroll
        for (int m = 0; m < 8; ++m) {
            b0 += wb[m] * fb[m].x;
            b1 += wb[m] * fb[m].y;
        }

        v4f v = {a0, a1, b0, b1};
        op[ip] = v;
    }
}

extern "C" void kernel_launch(void* const* d_in, const int* in_sizes, int n_in,
                              void* d_out, int out_size, void* d_ws, size_t ws_size,
                              hipStream_t stream) {
    const float* x      = (const float*)d_in[0];
    const float* tables = (const float*)d_in[1];
    float*       out    = (float*)d_out;
    const int N = in_sizes[0] / 3;
    const int blocks = (N + 255) / 256;
    hipLaunchKernelGGL(hashenc_kernel, dim3(blocks), dim3(256), 0, stream,
                       x, tables, out, N);
}

// Round 5
// 991.050 us; speedup vs baseline: 1.7050x; 1.0315x over previous
//
#include <hip/hip_runtime.h>

// Instant-NGP style multires hash encoding.
// N=2^20 points, 16 levels, table 2^19 entries x 2 features (float32).
//
// SEMANTICS LEDGER:
//  - q-path: XLA reciprocal-multiply rewrite, constexpr-precomputed table
//    (strict IEEE f32 per op, no contraction). Verified absmax 4.8e-07.
//  - corners/wrap/uint32 hash mod 2^19/weights/layout precision-robust.
//  - RESOLUTIONS trap: int(16 * 32**(9/15)) == 127, NOT 128.
//
// PERF LEDGER (this session):
//  R3: NT loads/stores -> FETCH 4.0GB, dur 1550us. NT kills L3 residency of
//      tables (~128x line reuse). REVERTED permanently.
//  R4: revert NT + level-pair ILP: dur ~950us (= baseline). VGPR stayed 32:
//      compiler refuses to keep 16 gathers in flight; ILP lever is dead.
//      Counters: VALUBusy 4.4%, HBM-equiv 43%, occ 71%, FETCH 3.0GB vs 76MB
//      ideal => transaction-throughput-bound on ~134M random 8B gathers
//      (every gather = L1+L2 miss = 1 L2 request + ~43B EA traffic).
//  R5 (this round): STRUCTURAL -- Morton counting-sort of points (32^3 bins,
//      ~32 pts/bin) so a wave's 64 lanes span ~2 cells: levels res<=127
//      (~62% of gathers) collapse onto few distinct addresses (TA same-addr
//      coalescing + L1/L2 residency). XCD-chunked swizzle gives each XCD a
//      contiguous Morton octant (mid-level footprint -> L2-resident).
//      Per-point math BYTE-IDENTICAL to R4 path; only thread<->point
//      assignment changes; output written to original row out[n].
//      Fallback to unsorted kernel if ws_size < ~4.5MB.

static constexpr int      kNLevels   = 16;
static constexpr unsigned kTableSize = 1u << 19;
static constexpr unsigned kMask      = kTableSize - 1u;
static constexpr unsigned kP1        = 2654435761u;
static constexpr unsigned kP2        = 805459861u;

static constexpr int kNBins = 32768;   // 32^3 Morton bins

typedef float v4f __attribute__((ext_vector_type(4)));
typedef float v2f __attribute__((ext_vector_type(2)));

// int(16 * 32**(i/15)) with exact Python-double semantics (note 127!)
constexpr int RES_[kNLevels]  = {16, 20, 25, 32, 40, 50, 64, 80,
                                 101, 127, 161, 203, 256, 322, 406, 512};
constexpr int QOFF_[kNLevels] = {0, 16, 36, 61, 93, 133, 183, 247,
                                 327, 428, 555, 716, 919, 1175, 1497, 1903};
static constexpr int kQTot = 2415;  // sum of RES_

// q(c,res) under XLA reciprocal-multiply semantics:
//   r = RN32(1/res); v = RN32(c*r); q = trunc(((v+1)*0.5)*262144)
constexpr unsigned qval_rcp(int c, int res) {
    const float r = 1.0f / (float)res;
    const float v = (float)c * r;
    const float s = ((v + 1.0f) * 0.5f) * 262144.0f;
    return (unsigned)s;
}

struct QTab {
    unsigned v[kQTot];
    constexpr QTab() : v{} {
        int o = 0;
        for (int i = 0; i < kNLevels; ++i) {
            for (int c = 0; c < RES_[i]; ++c) v[o + c] = qval_rcp(c, RES_[i]);
            o += RES_[i];
        }
    }
};
__constant__ QTab QT = QTab();

// ---------------- per-level index+weight (verified path, untouched) --------
__device__ __forceinline__ void level_idx_w(
    const int i, const unsigned* __restrict__ sq,
    const float px, const float py, const float pz,
    unsigned* __restrict__ idx, float* __restrict__ w)
{
    const int   res  = RES_[i];
    const float resf = (float)res;
    const unsigned* qt = sq + QOFF_[i];

    const float cxf = px * resf, cyf = py * resf, czf = pz * resf;
    const float fx = floorf(cxf), fy = floorf(cyf), fz = floorf(czf);
    const float lx = cxf - fx, ly = cyf - fy, lz = czf - fz;

    const int ix = (int)fx, iy = (int)fy, iz = (int)fz;
    const int cx0 = ix < 0 ? ix + res : (ix >= res ? ix - res : ix);
    const int cy0 = iy < 0 ? iy + res : (iy >= res ? iy - res : iy);
    const int cz0 = iz < 0 ? iz + res : (iz >= res ? iz - res : iz);
    const int cx1 = (cx0 + 1 == res) ? 0 : cx0 + 1;
    const int cy1 = (cy0 + 1 == res) ? 0 : cy0 + 1;
    const int cz1 = (cz0 + 1 == res) ? 0 : cz0 + 1;

    const unsigned qx0 = qt[cx0], qx1 = qt[cx1];
    const unsigned qy0 = qt[cy0], qy1 = qt[cy1];
    const unsigned qz0 = qt[cz0], qz1 = qt[cz1];

    const unsigned hy0 = qy0 * kP1, hy1 = qy1 * kP1;
    const unsigned hz0 = qz0 * kP2, hz1 = qz1 * kP2;

    const float wx0 = 1.0f - lx, wx1 = lx;
    const float wy0 = 1.0f - ly, wy1 = ly;
    const float wz0 = 1.0f - lz, wz1 = lz;

#pragma unroll
    for (int m = 0; m < 8; ++m) {
        const unsigned h = ((m & 4) ? qx1 : qx0) +
                           ((m & 2) ? hy1 : hy0) +
                           ((m & 1) ? hz1 : hz0);
        idx[m] = h & kMask;
        w[m] = (((m & 4) ? wx1 : wx0) * ((m & 2) ? wy1 : wy0)) *
               ((m & 1) ? wz1 : wz0);
    }
}

// core per-point body shared by sorted/unsorted kernels
__device__ __forceinline__ void encode_point(
    const unsigned* __restrict__ sq, const float* __restrict__ tables,
    float* __restrict__ out, const int n)
{
    float px = out ? 0.0f : 0.0f; // (dummy to keep signature simple; unused)
    (void)px;
    // actual loads done by caller-provided coords; see callers
}

// ---------------- Morton binning helpers ----------------------------------
__device__ __forceinline__ unsigned spread5(unsigned x) {
    // 5-bit "Part1By2" spread (subset of the 10-bit classic)
    x &= 0x3ffu;
    x = (x | (x << 16)) & 0x30000FFu;
    x = (x | (x << 8))  & 0x300F00Fu;
    x = (x | (x << 4))  & 0x30C30C3u;
    x = (x | (x << 2))  & 0x9249249u;
    return x;
}

__device__ __forceinline__ unsigned point_bin(const float* __restrict__ x, int n) {
    float px = fminf(fmaxf(x[3 * n + 0], -1.0f), 1.0f);
    float py = fminf(fmaxf(x[3 * n + 1], -1.0f), 1.0f);
    float pz = fminf(fmaxf(x[3 * n + 2], -1.0f), 1.0f);
    int cx = (int)((px + 1.0f) * 16.0f); cx = cx > 31 ? 31 : cx;
    int cy = (int)((py + 1.0f) * 16.0f); cy = cy > 31 ? 31 : cy;
    int cz = (int)((pz + 1.0f) * 16.0f); cz = cz > 31 ? 31 : cz;
    return spread5((unsigned)cx) | (spread5((unsigned)cy) << 1) |
           (spread5((unsigned)cz) << 2);
}

// ---------------- sort pipeline kernels ------------------------------------
__global__ void zero_kernel(unsigned* __restrict__ p, int n) {
    int i = blockIdx.x * 256 + threadIdx.x;
    if (i < n) p[i] = 0u;
}

__global__ void hist_kernel(const float* __restrict__ x,
                            unsigned* __restrict__ counts, int N) {
    int n = blockIdx.x * 256 + threadIdx.x;
    if (n >= N) return;
    atomicAdd(&counts[point_bin(x, n)], 1u);
}

// single-block exclusive scan of 32768 counts -> cursor (= bin start)
__global__ __launch_bounds__(1024) void scan_kernel(
    const unsigned* __restrict__ counts, unsigned* __restrict__ cursor) {
    __shared__ unsigned sh[1024];
    const int t = threadIdx.x;
    unsigned loc[32];
    unsigned s = 0;
#pragma unroll
    for (int j = 0; j < 32; ++j) { loc[j] = s; s += counts[t * 32 + j]; }
    sh[t] = s;
    __syncthreads();
    for (int off = 1; off < 1024; off <<= 1) {
        unsigned v = (t >= off) ? sh[t - off] : 0u;
        __syncthreads();
        sh[t] += v;
        __syncthreads();
    }
    const unsigned base = sh[t] - s;  // exclusive prefix of this thread's chunk
#pragma unroll
    for (int j = 0; j < 32; ++j) cursor[t * 32 + j] = base + loc[j];
}

__global__ void scatter_kernel(const float* __restrict__ x,
                               unsigned* __restrict__ cursor,
                               unsigned* __restrict__ perm, int N) {
    int n = blockIdx.x * 256 + threadIdx.x;
    if (n >= N) return;
    unsigned pos = atomicAdd(&cursor[point_bin(x, n)], 1u);
    perm[pos] = (unsigned)n;
}

// ---------------- main kernels ---------------------------------------------
template <bool SORTED>
__global__ __launch_bounds__(256, 6) void hashenc_kernel_t(
    const float* __restrict__ x,
    const float* __restrict__ tables,
    float* __restrict__ out,
    const unsigned* __restrict__ perm,
    int N)
{
    __shared__ unsigned sq[kQTot];
    for (int t = threadIdx.x; t < kQTot; t += 256) sq[t] = QT.v[t];
    __syncthreads();

    int bid = blockIdx.x;
    if (SORTED) {
        // XCD-chunked swizzle: each XCD gets a contiguous Morton range
        const int nblk = gridDim.x;
        if ((nblk & 7) == 0) bid = (bid & 7) * (nblk >> 3) + (bid >> 3);
    }
    const int g = bid * 256 + threadIdx.x;
    if (g >= N) return;
    const int n = SORTED ? (int)perm[g] : g;

    float px = x[3 * n + 0];
    float py = x[3 * n + 1];
    float pz = x[3 * n + 2];
    px = fminf(fmaxf(px, -1.0f), 1.0f);
    py = fminf(fmaxf(py, -1.0f), 1.0f);
    pz = fminf(fmaxf(pz, -1.0f), 1.0f);

    // output goes to the ORIGINAL row n (order preserved)
    v4f* op = (v4f*)(out + (size_t)n * (2 * kNLevels));

#pragma unroll
    for (int ip = 0; ip < kNLevels / 2; ++ip) {
        const int iA = 2 * ip, iB = 2 * ip + 1;

        unsigned ia[8], ib[8];
        float    wa[8], wb[8];
        level_idx_w(iA, sq, px, py, pz, ia, wa);
        level_idx_w(iB, sq, px, py, pz, ib, wb);

        const v2f* tA = (const v2f*)tables + (size_t)iA * kTableSize;
        const v2f* tB = (const v2f*)tables + (size_t)iB * kTableSize;

        v2f fa[8], fb[8];
#pragma unroll
        for (int m = 0; m < 8; ++m) fa[m] = tA[ia[m]];
#pragma unroll
        for (int m = 0; m < 8; ++m) fb[m] = tB[ib[m]];

        float a0 = 0.0f, a1 = 0.0f, b0 = 0.0f, b1 = 0.0f;
#pragma unroll
        for (int m = 0; m < 8; ++m) {
            a0 += wa[m] * fa[m].x;
            a1 += wa[m] * fa[m].y;
        }
#pragma unroll
        for (int m = 0; m < 8; ++m) {
            b0 += wb[m] * fb[m].x;
            b1 += wb[m] * fb[m].y;
        }

        v4f v = {a0, a1, b0, b1};
        op[ip] = v;
    }
}

extern "C" void kernel_launch(void* const* d_in, const int* in_sizes, int n_in,
                              void* d_out, int out_size, void* d_ws, size_t ws_size,
                              hipStream_t stream) {
    const float* x      = (const float*)d_in[0];
    const float* tables = (const float*)d_in[1];
    float*       out    = (float*)d_out;
    const int N = in_sizes[0] / 3;
    const int pb = (N + 255) / 256;

    const size_t need = ((size_t)2 * kNBins + (size_t)N) * sizeof(unsigned);
    if (d_ws != nullptr && ws_size >= need) {
        unsigned* counts = (unsigned*)d_ws;
        unsigned* cursor = counts + kNBins;
        unsigned* perm   = cursor + kNBins;

        hipLaunchKernelGGL(zero_kernel, dim3((kNBins + 255) / 256), dim3(256),
                           0, stream, counts, kNBins);
        hipLaunchKernelGGL(hist_kernel, dim3(pb), dim3(256), 0, stream,
                           x, counts, N);
        hipLaunchKernelGGL(scan_kernel, dim3(1), dim3(1024), 0, stream,
                           counts, cursor);
        hipLaunchKernelGGL(scatter_kernel, dim3(pb), dim3(256), 0, stream,
                           x, cursor, perm, N);
        hipLaunchKernelGGL((hashenc_kernel_t<true>), dim3(pb), dim3(256),
                           0, stream, x, tables, out, perm, N);
    } else {
        hipLaunchKernelGGL((hashenc_kernel_t<false>), dim3(pb), dim3(256),
                           0, stream, x, tables, out, nullptr, N);
    }
}